// Round 2
// baseline (105.501 us; speedup 1.0000x reference)
//
#include <hip/hip_runtime.h>
#include <hip/hip_bf16.h>

// Depthwise 1D conv, VALID, K=3.
// x:   (B=8, C=1024, N=8192) f32
// f:   (C=1024, K=3) f32
// out: (B=8, C=1024, N_out=8190) f32
//
// out[b,c,n] = x[n]*f0 + x[n+1]*f1 + x[n+2]*f2
//
// Memory-bound: ~537 MB total traffic -> floor ~85us at 6.3 TB/s copy ceiling.
// R2: 16B-aligned float4 stores. Row base byte offset = row*32760, which is
// 0 mod 16 for even rows and 8 mod 16 for odd rows. Peel 2 outputs per row
// (tail for even, head for odd) so the 2047 bulk stores per row are all
// 16B-aligned dwordx4. Parity branch is wave-uniform (one row per block).

#define C_DIM 1024
#define N_IN 8192
#define N_OUT 8190

__global__ __launch_bounds__(256) void dwconv1d_k3_kernel(
    const float* __restrict__ x,
    const float* __restrict__ filt,
    float* __restrict__ out)
{
    const int row = blockIdx.x;          // row = b*C + c, 8192 rows total
    const int c = row & (C_DIM - 1);     // C = 1024 (power of 2)

    const float f0 = filt[c * 3 + 0];
    const float f1 = filt[c * 3 + 1];
    const float f2 = filt[c * 3 + 2];

    const float* __restrict__ xr = x + (size_t)row * N_IN;   // 16B-aligned base
    float* __restrict__ orow = out + (size_t)row * N_OUT;

    if ((row & 1) == 0) {
        // Even row: orow is 16B-aligned. float4 stores at n=4g, g=0..2046;
        // tail outputs n=8188,8189.
        for (int g = threadIdx.x; g < 2047; g += 256) {
            const int n = g * 4;
            const float4 a = *reinterpret_cast<const float4*>(xr + n);      // 16B
            const float2 b = *reinterpret_cast<const float2*>(xr + n + 4);  // 8B halo
            float4 o;
            o.x = a.x * f0 + a.y * f1 + a.z * f2;
            o.y = a.y * f0 + a.z * f1 + a.w * f2;
            o.z = a.z * f0 + a.w * f1 + b.x * f2;
            o.w = a.w * f0 + b.x * f1 + b.y * f2;
            *reinterpret_cast<float4*>(orow + n) = o;  // 16B aligned
        }
        if (threadIdx.x == 0) {
            const float4 a = *reinterpret_cast<const float4*>(xr + 8188);
            float2 t;
            t.x = a.x * f0 + a.y * f1 + a.z * f2;
            t.y = a.y * f0 + a.z * f1 + a.w * f2;
            *reinterpret_cast<float2*>(orow + 8188) = t;  // 16B aligned
        }
    } else {
        // Odd row: orow byte offset is 8 mod 16. Head outputs n=0,1 (float2,
        // 8B-aligned); then float4 stores at n=2+4g -> byte offset
        // 8 + 8 + 16g -> 16B-aligned. g=0..2046 covers n=2..8189.
        for (int g = threadIdx.x; g < 2047; g += 256) {
            const int n = g * 4;
            const float2 p = *reinterpret_cast<const float2*>(xr + n + 2);  // 8B
            const float4 a = *reinterpret_cast<const float4*>(xr + n + 4);  // 16B
            float4 o;
            o.x = p.x * f0 + p.y * f1 + a.x * f2;
            o.y = p.y * f0 + a.x * f1 + a.y * f2;
            o.z = a.x * f0 + a.y * f1 + a.z * f2;
            o.w = a.y * f0 + a.z * f1 + a.w * f2;
            *reinterpret_cast<float4*>(orow + n + 2) = o;  // 16B aligned
        }
        if (threadIdx.x == 0) {
            const float4 a = *reinterpret_cast<const float4*>(xr);
            float2 h;
            h.x = a.x * f0 + a.y * f1 + a.z * f2;
            h.y = a.y * f0 + a.z * f1 + a.w * f2;
            *reinterpret_cast<float2*>(orow) = h;  // 8B aligned
        }
    }
}

extern "C" void kernel_launch(void* const* d_in, const int* in_sizes, int n_in,
                              void* d_out, int out_size, void* d_ws, size_t ws_size,
                              hipStream_t stream) {
    const float* x    = (const float*)d_in[0];
    const float* filt = (const float*)d_in[1];
    float* out        = (float*)d_out;

    const int rows = 8 * C_DIM;  // B * C = 8192
    dwconv1d_k3_kernel<<<rows, 256, 0, stream>>>(x, filt, out);
}

// Round 4
// 85.974 us; speedup vs baseline: 1.2271x; 1.2271x over previous
//
#include <hip/hip_runtime.h>
#include <hip/hip_bf16.h>

// Depthwise 1D conv, VALID, K=3.
// x:   (B=8, C=1024, N=8192) f32
// f:   (C=1024, K=3) f32
// out: (B=8, C=1024, N_out=8190) f32
//
// out[b,c,n] = x[n]*f0 + x[n+1]*f1 + x[n+2]*f2
//
// R4: same as R3 but with native clang ext_vector types so
// __builtin_nontemporal_store compiles (HIP_vector_type is a class, rejected).
// Batched unrolled loads (16 VMEM ops in flight per wave before compute)
// + nontemporal stores. Parity-aligned 16B stores kept from R2.
// Row base byte offset = row*32760: 0 mod 16 (even rows), 8 mod 16 (odd).

#define C_DIM 1024
#define N_IN 8192
#define N_OUT 8190

typedef float vfloat4 __attribute__((ext_vector_type(4)));
typedef float vfloat2 __attribute__((ext_vector_type(2)));

__global__ __launch_bounds__(256) void dwconv1d_k3_kernel(
    const float* __restrict__ x,
    const float* __restrict__ filt,
    float* __restrict__ out)
{
    const int row = blockIdx.x;          // row = b*C + c, 8192 rows
    const int c = row & (C_DIM - 1);
    const int tid = threadIdx.x;

    const float f0 = filt[c * 3 + 0];
    const float f1 = filt[c * 3 + 1];
    const float f2 = filt[c * 3 + 2];

    const float* __restrict__ xr = x + (size_t)row * N_IN;   // 16B-aligned
    float* __restrict__ orow = out + (size_t)row * N_OUT;

    vfloat4 a[8];
    vfloat2 b[8];

    if ((row & 1) == 0) {
        // Even row: orow 16B-aligned. Bulk groups g=0..2046 at n=4g.
        // Phase p, thread t -> g = 256p + t; only (p=7,t=255) is the
        // out-of-range g=2047: clamp its load, predicate its store.
        #pragma unroll
        for (int p = 0; p < 8; ++p) {
            int g = p * 256 + tid;
            g = (g > 2046) ? 2046 : g;
            const int n = g * 4;
            a[p] = *reinterpret_cast<const vfloat4*>(xr + n);      // 16B
            b[p] = *reinterpret_cast<const vfloat2*>(xr + n + 4);  // 8B halo
        }
        #pragma unroll
        for (int p = 0; p < 8; ++p) {
            const int g = p * 256 + tid;
            vfloat4 o;
            o.x = a[p].x * f0 + a[p].y * f1 + a[p].z * f2;
            o.y = a[p].y * f0 + a[p].z * f1 + a[p].w * f2;
            o.z = a[p].z * f0 + a[p].w * f1 + b[p].x * f2;
            o.w = a[p].w * f0 + b[p].x * f1 + b[p].y * f2;
            if (g < 2047)
                __builtin_nontemporal_store(o, reinterpret_cast<vfloat4*>(orow + g * 4));
        }
        if (tid == 0) {  // tail outputs n=8188,8189
            const vfloat4 t4 = *reinterpret_cast<const vfloat4*>(xr + 8188);
            vfloat2 t;
            t.x = t4.x * f0 + t4.y * f1 + t4.z * f2;
            t.y = t4.y * f0 + t4.z * f1 + t4.w * f2;
            __builtin_nontemporal_store(t, reinterpret_cast<vfloat2*>(orow + 8188));
        }
    } else {
        // Odd row: head outputs n=0,1; bulk stores at n=2+4g (16B-aligned).
        #pragma unroll
        for (int p = 0; p < 8; ++p) {
            int g = p * 256 + tid;
            g = (g > 2046) ? 2046 : g;
            const int n = g * 4;
            b[p] = *reinterpret_cast<const vfloat2*>(xr + n + 2);  // 8B
            a[p] = *reinterpret_cast<const vfloat4*>(xr + n + 4);  // 16B
        }
        #pragma unroll
        for (int p = 0; p < 8; ++p) {
            const int g = p * 256 + tid;
            vfloat4 o;
            o.x = b[p].x * f0 + b[p].y * f1 + a[p].x * f2;
            o.y = b[p].y * f0 + a[p].x * f1 + a[p].y * f2;
            o.z = a[p].x * f0 + a[p].y * f1 + a[p].z * f2;
            o.w = a[p].y * f0 + a[p].z * f1 + a[p].w * f2;
            if (g < 2047)
                __builtin_nontemporal_store(o, reinterpret_cast<vfloat4*>(orow + g * 4 + 2));
        }
        if (tid == 0) {  // head outputs n=0,1
            const vfloat4 h4 = *reinterpret_cast<const vfloat4*>(xr);
            vfloat2 h;
            h.x = h4.x * f0 + h4.y * f1 + h4.z * f2;
            h.y = h4.y * f0 + h4.z * f1 + h4.w * f2;
            __builtin_nontemporal_store(h, reinterpret_cast<vfloat2*>(orow));
        }
    }
}

extern "C" void kernel_launch(void* const* d_in, const int* in_sizes, int n_in,
                              void* d_out, int out_size, void* d_ws, size_t ws_size,
                              hipStream_t stream) {
    const float* x    = (const float*)d_in[0];
    const float* filt = (const float*)d_in[1];
    float* out        = (float*)d_out;

    const int rows = 8 * C_DIM;  // B * C = 8192
    dwconv1d_k3_kernel<<<rows, 256, 0, stream>>>(x, filt, out);
}